// Round 13
// baseline (489.130 us; speedup 1.0000x reference)
//
#include <hip/hip_runtime.h>
#include <hip/hip_bf16.h>
#include <math.h>

// Problem constants (PoseMixtureVAE)
#define N_BATCH 4096
#define FRAME   267
#define LATENT  32
#define HIDDEN  256
#define EXPERTS 6

typedef __hip_bfloat16 bf16;
typedef __bf16  bf16x8 __attribute__((ext_vector_type(8)));
typedef float   f32x4  __attribute__((ext_vector_type(4)));

__device__ __forceinline__ float eluf(float v) { return (v > 0.f) ? v : (expf(v) - 1.f); }

// ---------------------------------------------------------------------------
// Weight repack: src f32 [E][Ksrc][M] -> dst bf16 [E][Kst][Mtot][32]
// (k-block contiguous, split-k mapping: dst k' = kBase + (srcK - srcRow0)).
// Each block = one 32x32 (k' x m) tile.
// ---------------------------------------------------------------------------
struct WEnt { const float* src; bf16* dst;
              int Ksrc, Klen, srcRow0, kBase, kt0, nKt, Kst, M, Mtiles, Mtot, mOff, E, cum; };
struct WTab { WEnt e[14]; int total; };

__global__ __launch_bounds__(256) void wtr_kernel(WTab tab) {
    __shared__ float tbuf[32][33];
    const int tid = threadIdx.x, bid = blockIdx.x;
    int i = 0;
    while (i < 13 && bid >= tab.e[i + 1].cum) ++i;
    const WEnt en = tab.e[i];
    int t = bid - en.cum;
    const int perE = en.nKt * en.Mtiles;
    const int e = t / perE;  t -= e * perE;
    const int ktR = t / en.Mtiles, mt = t - ktR * en.Mtiles;
    const int ktA = en.kt0 + ktR;
    const int tx = tid & 31, ty = tid >> 5;
    #pragma unroll
    for (int i0 = 0; i0 < 32; i0 += 8) {
        const int kp  = ktA * 32 + i0 + ty;
        const int rel = kp - en.kBase;
        const int m   = mt * 32 + tx;
        float v = 0.f;
        if (rel >= 0 && rel < en.Klen && m < en.M)
            v = en.src[((size_t)e * en.Ksrc + en.srcRow0 + rel) * en.M + m];
        tbuf[i0 + ty][tx] = v;
    }
    __syncthreads();
    bf16* d = en.dst + ((size_t)(e * en.Kst + ktA) * en.Mtot + en.mOff + mt * 32) * 32;
    #pragma unroll
    for (int i0 = 0; i0 < 32; i0 += 8)
        d[(size_t)(i0 + ty) * 32 + tx] = __float2bfloat16(tbuf[tx][i0 + ty]);
}

// ---------------------------------------------------------------------------
// Pipeline kernel. Grid (4, 256): block (g, r) carries 16-row block r through
// all stages; col-group g (64 cols). Cross-block deps are per-row 4-way flags.
// LDS A layouts (k'):
//  S1 h1 : 576 = [x 0..266 | 0 | c 288..554 | 0]
//  S2 h2 : 544 = [x | 0 | h1 288..543]
//  S3 mid: 544 = [x | 0 | h2 288..543]
//  S4 d1 : 320 = [z 0..31 | c 32..298 | 0]    (also feeds gate chain)
//  S5/S6 : 288 = [z | d* 32..287]
// ---------------------------------------------------------------------------
#define STRA 584   // LDS A row stride (bf16): fits Kpad<=576, 16B-aligned

__device__ __forceinline__ void seg_f32(bf16* sA, int kOff, const float* __restrict__ src,
                                        int ld, int cols, int alloc, int row0, int tid) {
    const int r = tid >> 4, c0 = (tid & 15) * 8;
    const float* s = src + (size_t)(row0 + r) * ld;
    for (int kb = c0; kb < alloc; kb += 128) {
        bf16 tmp[8];
        #pragma unroll
        for (int j = 0; j < 8; ++j) tmp[j] = __float2bfloat16((kb + j < cols) ? s[kb + j] : 0.f);
        *(float4*)(sA + r * STRA + kOff + kb) = *(float4*)tmp;
    }
}
__device__ __forceinline__ void seg_bf16(bf16* sA, int kOff, const bf16* __restrict__ src,
                                         int ld, int cols, int row0, int tid) {
    const int r = tid >> 4, c0 = (tid & 15) * 8;
    const bf16* s = src + (size_t)(row0 + r) * ld;
    for (int kb = c0; kb < cols; kb += 128)
        *(float4*)(sA + r * STRA + kOff + kb) = *(const float4*)(s + kb);
}
__device__ __forceinline__ void seg_lds(bf16* sA, const bf16* sZ, int tid) {
    const int r = tid >> 4, c0 = (tid & 15) * 8;
    if (c0 < 32) *(float4*)(sA + r * STRA + c0) = *(const float4*)(sZ + r * 32 + c0);
}

// producer: all block stores done -> fence -> count arrival (4 per row flag)
__device__ __forceinline__ void signal4(unsigned* f) {
    __syncthreads();
    if (threadIdx.x == 0) {
        __threadfence();
        __hip_atomic_fetch_add(f, 1u, __ATOMIC_RELAXED, __HIP_MEMORY_SCOPE_AGENT);
    }
}
// consumer: spin (relaxed, acquire every 1024) until all 4 producers arrived
__device__ __forceinline__ void wait4(unsigned* f) {
    if (threadIdx.x == 0) {
        unsigned spins = 0;
        for (;;) {
            unsigned v = ((++spins & 1023u) == 0u)
                ? __hip_atomic_load(f, __ATOMIC_ACQUIRE, __HIP_MEMORY_SCOPE_AGENT)
                : __hip_atomic_load(f, __ATOMIC_RELAXED, __HIP_MEMORY_SCOPE_AGENT);
            if (v >= 4u) break;
            __builtin_amdgcn_s_sleep(1);
        }
        __threadfence();
    }
    __syncthreads();
}

template<int KST, int E>
__device__ __forceinline__ f32x4 wave_gemm(const bf16* __restrict__ Wt, int Mtot, int col,
    const bf16* __restrict__ sA, const float* __restrict__ bias, int M,
    const float* __restrict__ sCo, int ml, int quad)
{
    f32x4 acc = (f32x4){0.f, 0.f, 0.f, 0.f};
    for (int e = 0; e < E; ++e) {
        f32x4 p = (f32x4){0.f, 0.f, 0.f, 0.f};
        const bf16* wp = Wt + ((size_t)e * KST * Mtot + col) * 32 + quad * 8;
        #pragma unroll
        for (int ks = 0; ks < KST; ++ks) {
            const bf16x8 b  = *(const bf16x8*)(wp + (size_t)ks * Mtot * 32);
            const bf16x8 av = *(const bf16x8*)(sA + ml * STRA + ks * 32 + quad * 8);
            p = __builtin_amdgcn_mfma_f32_16x16x32_bf16(av, b, p, 0, 0, 0);
        }
        const float bv = (col < M) ? bias[(size_t)e * M + col] : 0.f;
        #pragma unroll
        for (int rg = 0; rg < 4; ++rg) {
            const float s = sCo ? sCo[e * 16 + quad * 4 + rg] : 1.f;
            acc[rg] += s * (p[rg] + bv);
        }
    }
    return acc;
}

struct PArgs {
    const float *x, *c, *eps;
    const float *enc_b1, *enc_b2, *enc_bmu, *enc_blv, *g_b0, *g_b1, *g_b2, *b0, *b1, *b2;
    float *out_layer, *out_mu, *out_lv;
    unsigned* flags;                     // [4][256], memset 0 per call
    bf16 *h1buf, *h2buf, *d1buf, *d2buf; // [4096][256]
    bf16 *Wt_e1, *Wt_e2, *Wt_ml, *Wt_g0, *Wt_g1, *Wt_g2, *Wt_w0, *Wt_w1, *Wt_w2;
};

__global__ __launch_bounds__(256, 4) void pipe_kernel(PArgs a) {
    __shared__ bf16  sA[16 * STRA];          // 18688B
    __shared__ char  scr[5632];              // sML(4KB) / sG1+sG2+sLg
    __shared__ bf16  sZ[16 * 32];            // z persists S3..S6
    __shared__ float sCo[16 * EXPERTS];      // coeff persists S4..S6
    const int tid = threadIdx.x;
    const int g = blockIdx.x, r = blockIdx.y, row0 = r * 16;
    const int w = tid >> 6, lane = tid & 63, ml = lane & 15, quad = lane >> 4;
    const int colg = g * 64 + 16 * w + ml;
    unsigned* f = a.flags;

    // ---- S1: h1 = elu([x|0|c] @ W1 + b1), cols colg ----
    seg_f32(sA, 0,   a.x, FRAME, 267, 288, row0, tid);
    seg_f32(sA, 288, a.c, FRAME, 267, 288, row0, tid);
    __syncthreads();
    {
        f32x4 acc = wave_gemm<18, 1>(a.Wt_e1, 256, colg, sA, a.enc_b1, 256, nullptr, ml, quad);
        #pragma unroll
        for (int rg = 0; rg < 4; ++rg)
            a.h1buf[(size_t)(row0 + quad * 4 + rg) * 256 + colg] = __float2bfloat16(eluf(acc[rg]));
    }
    signal4(f + 0 * 256 + r);

    // ---- S2: h2 = elu([x|0|h1] @ W2 + b2) ----
    wait4(f + 0 * 256 + r);
    seg_f32 (sA, 0,   a.x, FRAME, 267, 288, row0, tid);
    seg_bf16(sA, 288, a.h1buf, 256, 256, row0, tid);
    __syncthreads();
    {
        f32x4 acc = wave_gemm<17, 1>(a.Wt_e2, 256, colg, sA, a.enc_b2, 256, nullptr, ml, quad);
        #pragma unroll
        for (int rg = 0; rg < 4; ++rg)
            a.h2buf[(size_t)(row0 + quad * 4 + rg) * 256 + colg] = __float2bfloat16(eluf(acc[rg]));
    }
    signal4(f + 1 * 256 + r);

    // ---- S3: mid (mu|lv GEMM + z), redundant per col-block, all local ----
    wait4(f + 1 * 256 + r);
    seg_f32 (sA, 0,   a.x, FRAME, 267, 288, row0, tid);
    seg_bf16(sA, 288, a.h2buf, 256, 256, row0, tid);
    __syncthreads();
    float* sML = (float*)scr;                          // 16x64 f32
    {
        const int col = 16 * w + ml;                   // 0..63
        f32x4 p = (f32x4){0.f, 0.f, 0.f, 0.f};
        const bf16* wp = a.Wt_ml + (size_t)col * 32 + quad * 8;
        #pragma unroll
        for (int ks = 0; ks < 17; ++ks) {
            const bf16x8 b  = *(const bf16x8*)(wp + (size_t)ks * 64 * 32);
            const bf16x8 av = *(const bf16x8*)(sA + ml * STRA + ks * 32 + quad * 8);
            p = __builtin_amdgcn_mfma_f32_16x16x32_bf16(av, b, p, 0, 0, 0);
        }
        const float bv = (col < 32) ? a.enc_bmu[col] : a.enc_blv[col - 32];
        #pragma unroll
        for (int rg = 0; rg < 4; ++rg)
            sML[(quad * 4 + rg) * 64 + col] = p[rg] + bv;
    }
    __syncthreads();
    for (int i = tid; i < 16 * 32; i += 256) {
        const int rr = i >> 5, l = i & 31;
        const float m  = sML[rr * 64 + l];
        const float lv = sML[rr * 64 + 32 + l];
        const int gi = (row0 + rr) * LATENT + l;
        if (g == 0) { a.out_mu[gi] = m; a.out_lv[gi] = lv; }
        sZ[rr * 32 + l] = __float2bfloat16(m + a.eps[gi] * expf(0.5f * lv));
    }
    __syncthreads();

    // ---- S4: stage [z|c]; gate chain (local); d1 ----
    seg_lds(sA, sZ, tid);
    seg_f32(sA, 32, a.c, FRAME, 267, 288, row0, tid);
    __syncthreads();
    bf16*  sG1 = (bf16*)scr;                 // 16x72
    bf16*  sG2 = (bf16*)(scr + 2304);
    float* sLg = (float*)(scr + 4608);       // 16x16
    {
        const int col = 16 * w + ml;
        f32x4 acc = wave_gemm<10, 1>(a.Wt_g0, 64, col, sA, a.g_b0, 64, nullptr, ml, quad);
        #pragma unroll
        for (int rg = 0; rg < 4; ++rg)
            sG1[(quad * 4 + rg) * 72 + col] = __float2bfloat16(eluf(acc[rg]));
    }
    __syncthreads();
    {
        const int col = 16 * w + ml;
        f32x4 p = (f32x4){0.f, 0.f, 0.f, 0.f};
        const bf16* wp = a.Wt_g1 + (size_t)col * 32 + quad * 8;
        #pragma unroll
        for (int ks = 0; ks < 2; ++ks) {
            const bf16x8 b  = *(const bf16x8*)(wp + (size_t)ks * 64 * 32);
            const bf16x8 av = *(const bf16x8*)(sG1 + ml * 72 + ks * 32 + quad * 8);
            p = __builtin_amdgcn_mfma_f32_16x16x32_bf16(av, b, p, 0, 0, 0);
        }
        const float bv = a.g_b1[col];
        #pragma unroll
        for (int rg = 0; rg < 4; ++rg)
            sG2[(quad * 4 + rg) * 72 + col] = __float2bfloat16(eluf(p[rg] + bv));
    }
    __syncthreads();
    if (w == 0) {
        f32x4 p = (f32x4){0.f, 0.f, 0.f, 0.f};
        const bf16* wp = a.Wt_g2 + (size_t)ml * 32 + quad * 8;
        #pragma unroll
        for (int ks = 0; ks < 2; ++ks) {
            const bf16x8 b  = *(const bf16x8*)(wp + (size_t)ks * 32 * 32);
            const bf16x8 av = *(const bf16x8*)(sG2 + ml * 72 + ks * 32 + quad * 8);
            p = __builtin_amdgcn_mfma_f32_16x16x32_bf16(av, b, p, 0, 0, 0);
        }
        const float bv = (ml < EXPERTS) ? a.g_b2[ml] : 0.f;
        #pragma unroll
        for (int rg = 0; rg < 4; ++rg)
            sLg[(quad * 4 + rg) * 16 + ml] = p[rg] + bv;
    }
    __syncthreads();
    if (tid < 16) {
        float v[EXPERTS];
        float m = -1e30f;
        #pragma unroll
        for (int i = 0; i < EXPERTS; ++i) { v[i] = sLg[tid * 16 + i]; m = fmaxf(m, v[i]); }
        float s = 0.f;
        #pragma unroll
        for (int i = 0; i < EXPERTS; ++i) { v[i] = expf(v[i] - m); s += v[i]; }
        const float inv = 1.f / s;
        #pragma unroll
        for (int i = 0; i < EXPERTS; ++i) sCo[i * 16 + tid] = v[i] * inv;
    }
    __syncthreads();
    {
        f32x4 acc = wave_gemm<10, EXPERTS>(a.Wt_w0, 256, colg, sA, a.b0, 256, sCo, ml, quad);
        #pragma unroll
        for (int rg = 0; rg < 4; ++rg)
            a.d1buf[(size_t)(row0 + quad * 4 + rg) * 256 + colg] = __float2bfloat16(eluf(acc[rg]));
    }
    signal4(f + 2 * 256 + r);

    // ---- S5: d2 = elu(moe([z|d1])) ----
    wait4(f + 2 * 256 + r);
    seg_lds(sA, sZ, tid);
    seg_bf16(sA, 32, a.d1buf, 256, 256, row0, tid);
    __syncthreads();
    {
        f32x4 acc = wave_gemm<9, EXPERTS>(a.Wt_w1, 256, colg, sA, a.b1, 256, sCo, ml, quad);
        #pragma unroll
        for (int rg = 0; rg < 4; ++rg)
            a.d2buf[(size_t)(row0 + quad * 4 + rg) * 256 + colg] = __float2bfloat16(eluf(acc[rg]));
    }
    signal4(f + 3 * 256 + r);

    // ---- S6: out = moe([z|d2]) -> d_out (f32) ----
    wait4(f + 3 * 256 + r);
    seg_lds(sA, sZ, tid);
    seg_bf16(sA, 32, a.d2buf, 256, 256, row0, tid);
    __syncthreads();
    {
        f32x4 acc = wave_gemm<9, EXPERTS>(a.Wt_w2, 320, colg, sA, a.b2, FRAME, sCo, ml, quad);
        #pragma unroll
        for (int rg = 0; rg < 4; ++rg)
            if (colg < FRAME)
                a.out_layer[(size_t)(row0 + quad * 4 + rg) * FRAME + colg] = acc[rg];
    }
    if (g == 0 && w == 0) {   // tail tile: cols 256..266
        const int col2 = 256 + ml;
        f32x4 acc = wave_gemm<9, EXPERTS>(a.Wt_w2, 320, col2, sA, a.b2, FRAME, sCo, ml, quad);
        #pragma unroll
        for (int rg = 0; rg < 4; ++rg)
            if (col2 < FRAME)
                a.out_layer[(size_t)(row0 + quad * 4 + rg) * FRAME + col2] = acc[rg];
    }
}

// ---------------------------------------------------------------------------
extern "C" void kernel_launch(void* const* d_in, const int* in_sizes, int n_in,
                              void* d_out, int out_size, void* d_ws, size_t ws_size,
                              hipStream_t stream) {
    PArgs a;
    a.x       = (const float*)d_in[0];
    a.c       = (const float*)d_in[1];
    a.eps     = (const float*)d_in[2];
    const float* enc_w1  = (const float*)d_in[3];
    a.enc_b1  = (const float*)d_in[4];
    const float* enc_w2  = (const float*)d_in[5];
    a.enc_b2  = (const float*)d_in[6];
    const float* enc_wmu = (const float*)d_in[7];
    a.enc_bmu = (const float*)d_in[8];
    const float* enc_wlv = (const float*)d_in[9];
    a.enc_blv = (const float*)d_in[10];
    const float* g_w0    = (const float*)d_in[11];
    a.g_b0    = (const float*)d_in[12];
    const float* g_w1    = (const float*)d_in[13];
    a.g_b1    = (const float*)d_in[14];
    const float* g_w2    = (const float*)d_in[15];
    a.g_b2    = (const float*)d_in[16];
    const float* w0      = (const float*)d_in[17];
    a.b0      = (const float*)d_in[18];
    const float* w1      = (const float*)d_in[19];
    a.b1      = (const float*)d_in[20];
    const float* w2      = (const float*)d_in[21];
    a.b2      = (const float*)d_in[22];

    a.out_layer = (float*)d_out;
    a.out_mu    = a.out_layer + (size_t)N_BATCH * FRAME;
    a.out_lv    = a.out_mu    + (size_t)N_BATCH * LATENT;

    // ---- workspace ----
    char* p = (char*)d_ws;
    a.flags = (unsigned*)p;  p += 4096;
    a.h1buf = (bf16*)p;      p += (size_t)N_BATCH * 256 * 2;
    a.h2buf = (bf16*)p;      p += (size_t)N_BATCH * 256 * 2;
    a.d1buf = (bf16*)p;      p += (size_t)N_BATCH * 256 * 2;
    a.d2buf = (bf16*)p;      p += (size_t)N_BATCH * 256 * 2;
    a.Wt_e1 = (bf16*)p;      p += (size_t)18 * 256 * 32 * 2;
    a.Wt_e2 = (bf16*)p;      p += (size_t)17 * 256 * 32 * 2;
    a.Wt_ml = (bf16*)p;      p += (size_t)17 * 64 * 32 * 2;
    a.Wt_g0 = (bf16*)p;      p += (size_t)10 * 64 * 32 * 2;
    a.Wt_g1 = (bf16*)p;      p += (size_t)2 * 64 * 32 * 2;
    a.Wt_g2 = (bf16*)p;      p += (size_t)2 * 32 * 32 * 2;
    a.Wt_w0 = (bf16*)p;      p += (size_t)EXPERTS * 10 * 256 * 32 * 2;
    a.Wt_w1 = (bf16*)p;      p += (size_t)EXPERTS * 9 * 256 * 32 * 2;
    a.Wt_w2 = (bf16*)p;      p += (size_t)EXPERTS * 9 * 320 * 32 * 2;

    WTab tab;
    int cum = 0, n = 0;
    auto add = [&](const float* src, bf16* dst, int Ksrc, int Klen, int srcRow0,
                   int kBase, int kt0, int nKt, int Kst, int M, int Mtot, int mOff, int E) {
        const int Mtiles = (M + 31) / 32;
        tab.e[n] = {src, dst, Ksrc, Klen, srcRow0, kBase, kt0, nKt, Kst, M, Mtiles, Mtot, mOff, E, cum};
        cum += E * nKt * Mtiles;
        ++n;
    };
    //   src      dst      Ksrc Klen row0 kBase kt0 nKt Kst  M   Mtot mOff E
    add(enc_w1,  a.Wt_e1,  534, 267, 0,   0,    0,  9,  18, 256, 256, 0,  1);
    add(enc_w1,  a.Wt_e1,  534, 267, 267, 288,  9,  9,  18, 256, 256, 0,  1);
    add(enc_w2,  a.Wt_e2,  523, 267, 0,   0,    0,  9,  17, 256, 256, 0,  1);
    add(enc_w2,  a.Wt_e2,  523, 256, 267, 288,  9,  8,  17, 256, 256, 0,  1);
    add(enc_wmu, a.Wt_ml,  523, 267, 0,   0,    0,  9,  17, 32,  64,  0,  1);
    add(enc_wmu, a.Wt_ml,  523, 256, 267, 288,  9,  8,  17, 32,  64,  0,  1);
    add(enc_wlv, a.Wt_ml,  523, 267, 0,   0,    0,  9,  17, 32,  64,  32, 1);
    add(enc_wlv, a.Wt_ml,  523, 256, 267, 288,  9,  8,  17, 32,  64,  32, 1);
    add(g_w0,    a.Wt_g0,  299, 299, 0,   0,    0,  10, 10, 64,  64,  0,  1);
    add(g_w1,    a.Wt_g1,  64,  64,  0,   0,    0,  2,  2,  64,  64,  0,  1);
    add(g_w2,    a.Wt_g2,  64,  64,  0,   0,    0,  2,  2,  6,   32,  0,  1);
    add(w0,      a.Wt_w0,  299, 299, 0,   0,    0,  10, 10, 256, 256, 0,  EXPERTS);
    add(w1,      a.Wt_w1,  288, 288, 0,   0,    0,  9,  9,  256, 256, 0,  EXPERTS);
    add(w2,      a.Wt_w2,  288, 288, 0,   0,    0,  9,  9,  267, 320, 0,  EXPERTS);
    tab.total = cum;   // 1738

    hipMemsetAsync(a.flags, 0, 4096, stream);
    wtr_kernel<<<dim3(cum), dim3(256), 0, stream>>>(tab);
    pipe_kernel<<<dim3(4, 256), dim3(256), 0, stream>>>(a);
}

// Round 14
// 232.255 us; speedup vs baseline: 2.1060x; 2.1060x over previous
//
#include <hip/hip_runtime.h>
#include <hip/hip_bf16.h>
#include <math.h>

// Problem constants (PoseMixtureVAE)
#define N_BATCH 4096
#define FRAME   267
#define LATENT  32
#define HIDDEN  256
#define EXPERTS 6

typedef __hip_bfloat16 bf16;
typedef __bf16  bf16x8 __attribute__((ext_vector_type(8)));
typedef float   f32x4  __attribute__((ext_vector_type(4)));

__device__ __forceinline__ float eluf(float v) { return (v > 0.f) ? v : (expf(v) - 1.f); }

// ---------------------------------------------------------------------------
// Weight repack: src f32 [E][Ksrc][M] -> dst bf16 [E][Kst][Mtot][32]
// (k-block contiguous, split-k mapping: dst k' = kBase + (srcK - srcRow0)).
// Each block = one 32x32 (k' x m) tile. (R13-validated.)
// ---------------------------------------------------------------------------
struct WEnt { const float* src; bf16* dst;
              int Ksrc, Klen, srcRow0, kBase, kt0, nKt, Kst, M, Mtiles, Mtot, mOff, E, cum; };
struct WTab { WEnt e[14]; int total; };

__global__ __launch_bounds__(256) void wtr_kernel(WTab tab) {
    __shared__ float tbuf[32][33];
    const int tid = threadIdx.x, bid = blockIdx.x;
    int i = 0;
    while (i < 13 && bid >= tab.e[i + 1].cum) ++i;
    const WEnt en = tab.e[i];
    int t = bid - en.cum;
    const int perE = en.nKt * en.Mtiles;
    const int e = t / perE;  t -= e * perE;
    const int ktR = t / en.Mtiles, mt = t - ktR * en.Mtiles;
    const int ktA = en.kt0 + ktR;
    const int tx = tid & 31, ty = tid >> 5;
    #pragma unroll
    for (int i0 = 0; i0 < 32; i0 += 8) {
        const int kp  = ktA * 32 + i0 + ty;
        const int rel = kp - en.kBase;
        const int m   = mt * 32 + tx;
        float v = 0.f;
        if (rel >= 0 && rel < en.Klen && m < en.M)
            v = en.src[((size_t)e * en.Ksrc + en.srcRow0 + rel) * en.M + m];
        tbuf[i0 + ty][tx] = v;
    }
    __syncthreads();
    bf16* d = en.dst + ((size_t)(e * en.Kst + ktA) * en.Mtot + en.mOff + mt * 32) * 32;
    #pragma unroll
    for (int i0 = 0; i0 < 32; i0 += 8)
        d[(size_t)(i0 + ty) * 32 + tx] = __float2bfloat16(tbuf[tx][i0 + ty]);
}

// ---------------------------------------------------------------------------
// LDS A staging helpers (R13-validated). STRA = row stride (bf16).
// ---------------------------------------------------------------------------
#define STRA 584

__device__ __forceinline__ void seg_f32(bf16* sA, int kOff, const float* __restrict__ src,
                                        int ld, int cols, int alloc, int row0, int tid) {
    const int r = tid >> 4, c0 = (tid & 15) * 8;
    const float* s = src + (size_t)(row0 + r) * ld;
    for (int kb = c0; kb < alloc; kb += 128) {
        bf16 tmp[8];
        #pragma unroll
        for (int j = 0; j < 8; ++j) tmp[j] = __float2bfloat16((kb + j < cols) ? s[kb + j] : 0.f);
        *(float4*)(sA + r * STRA + kOff + kb) = *(float4*)tmp;
    }
}
__device__ __forceinline__ void seg_bf16(bf16* sA, int kOff, const bf16* __restrict__ src,
                                         int ld, int cols, int row0, int tid) {
    const int r = tid >> 4, c0 = (tid & 15) * 8;
    const bf16* s = src + (size_t)(row0 + r) * ld;
    for (int kb = c0; kb < cols; kb += 128)
        *(float4*)(sA + r * STRA + kOff + kb) = *(const float4*)(s + kb);
}

template<int KST, int E>
__device__ __forceinline__ f32x4 wave_gemm(const bf16* __restrict__ Wt, int Mtot, int col,
    const bf16* __restrict__ sA, const float* __restrict__ bias, int M,
    const float* __restrict__ sCo, int ml, int quad)
{
    f32x4 acc = (f32x4){0.f, 0.f, 0.f, 0.f};
    for (int e = 0; e < E; ++e) {
        f32x4 p = (f32x4){0.f, 0.f, 0.f, 0.f};
        const bf16* wp = Wt + ((size_t)e * KST * Mtot + col) * 32 + quad * 8;
        #pragma unroll
        for (int ks = 0; ks < KST; ++ks) {
            const bf16x8 b  = *(const bf16x8*)(wp + (size_t)ks * Mtot * 32);
            const bf16x8 av = *(const bf16x8*)(sA + ml * STRA + ks * 32 + quad * 8);
            p = __builtin_amdgcn_mfma_f32_16x16x32_bf16(av, b, p, 0, 0, 0);
        }
        const float bv = (col < M) ? bias[(size_t)e * M + col] : 0.f;
        #pragma unroll
        for (int rg = 0; rg < 4; ++rg) {
            const float s = sCo ? sCo[e * 16 + quad * 4 + rg] : 1.f;
            acc[rg] += s * (p[rg] + bv);
        }
    }
    return acc;
}

// ---------------------------------------------------------------------------
// Encoder stage: out[r, colg] = elu([x | 0 | part2] @ W + b). Grid (4, 256).
//   P2F32: part2 is f32 (c) at kOff 288 (alloc 288) else bf16 (256 cols).
// ---------------------------------------------------------------------------
template<int KST, bool P2F32>
__global__ __launch_bounds__(256, 4) void enc_kernel(
    const float* __restrict__ x, const float* __restrict__ p2f,
    const bf16* __restrict__ p2b, const bf16* __restrict__ Wt,
    const float* __restrict__ bias, bf16* __restrict__ out)
{
    __shared__ bf16 sA[16 * STRA];
    const int tid = threadIdx.x;
    const int g = blockIdx.x, row0 = blockIdx.y * 16;
    const int w = tid >> 6, lane = tid & 63, ml = lane & 15, quad = lane >> 4;
    const int colg = g * 64 + 16 * w + ml;

    seg_f32(sA, 0, x, FRAME, 267, 288, row0, tid);
    if constexpr (P2F32) seg_f32(sA, 288, p2f, FRAME, 267, 288, row0, tid);
    else                 seg_bf16(sA, 288, p2b, 256, 256, row0, tid);
    __syncthreads();
    f32x4 acc = wave_gemm<KST, 1>(Wt, 256, colg, sA, bias, 256, nullptr, ml, quad);
    #pragma unroll
    for (int rg = 0; rg < 4; ++rg)
        out[(size_t)(row0 + quad * 4 + rg) * 256 + colg] = __float2bfloat16(eluf(acc[rg]));
}

// ---------------------------------------------------------------------------
// mid + d1: mu|lv GEMM (redundant per col-group) + z + gate chain + softmax,
// then d1 = elu(moe([z|c], w0, b0)). g==0 writes mu/lv/z/co. (R13-validated.)
// ---------------------------------------------------------------------------
struct MArgs {
    const float *x, *c, *eps;
    const float *enc_bmu, *enc_blv, *g_b0, *g_b1, *g_b2, *b0;
    const bf16 *h2buf, *Wt_ml, *Wt_g0, *Wt_g1, *Wt_g2, *Wt_w0;
    float *out_mu, *out_lv, *cobuf;
    bf16 *zbuf, *d1buf;
};

__global__ __launch_bounds__(256, 4) void mid_d1_kernel(MArgs a) {
    __shared__ bf16  sA[16 * STRA];
    __shared__ char  scr[5632];
    __shared__ bf16  sZ[16 * 32];
    __shared__ float sCo[16 * EXPERTS];
    const int tid = threadIdx.x;
    const int g = blockIdx.x, row0 = blockIdx.y * 16;
    const int w = tid >> 6, lane = tid & 63, ml = lane & 15, quad = lane >> 4;
    const int colg = g * 64 + 16 * w + ml;

    // mid GEMM input [x | 0 | h2]
    seg_f32 (sA, 0,   a.x, FRAME, 267, 288, row0, tid);
    seg_bf16(sA, 288, a.h2buf, 256, 256, row0, tid);
    __syncthreads();
    float* sML = (float*)scr;
    {
        const int col = 16 * w + ml;
        f32x4 p = (f32x4){0.f, 0.f, 0.f, 0.f};
        const bf16* wp = a.Wt_ml + (size_t)col * 32 + quad * 8;
        #pragma unroll
        for (int ks = 0; ks < 17; ++ks) {
            const bf16x8 b  = *(const bf16x8*)(wp + (size_t)ks * 64 * 32);
            const bf16x8 av = *(const bf16x8*)(sA + ml * STRA + ks * 32 + quad * 8);
            p = __builtin_amdgcn_mfma_f32_16x16x32_bf16(av, b, p, 0, 0, 0);
        }
        const float bv = (col < 32) ? a.enc_bmu[col] : a.enc_blv[col - 32];
        #pragma unroll
        for (int rg = 0; rg < 4; ++rg)
            sML[(quad * 4 + rg) * 64 + col] = p[rg] + bv;
    }
    __syncthreads();
    for (int i = tid; i < 16 * 32; i += 256) {
        const int rr = i >> 5, l = i & 31;
        const float m  = sML[rr * 64 + l];
        const float lv = sML[rr * 64 + 32 + l];
        const int gi = (row0 + rr) * LATENT + l;
        const bf16 zb = __float2bfloat16(m + a.eps[gi] * expf(0.5f * lv));
        sZ[rr * 32 + l] = zb;
        if (g == 0) { a.out_mu[gi] = m; a.out_lv[gi] = lv; a.zbuf[gi] = zb; }
    }
    __syncthreads();

    // stage [z | c]
    {
        const int r = tid >> 4, c0 = (tid & 15) * 8;
        if (c0 < 32) *(float4*)(sA + r * STRA + c0) = *(const float4*)(sZ + r * 32 + c0);
    }
    seg_f32(sA, 32, a.c, FRAME, 267, 288, row0, tid);
    bf16*  sG1 = (bf16*)scr;
    bf16*  sG2 = (bf16*)(scr + 2304);
    float* sLg = (float*)(scr + 4608);
    __syncthreads();
    {   // g1
        const int col = 16 * w + ml;
        f32x4 acc = wave_gemm<10, 1>(a.Wt_g0, 64, col, sA, a.g_b0, 64, nullptr, ml, quad);
        #pragma unroll
        for (int rg = 0; rg < 4; ++rg)
            sG1[(quad * 4 + rg) * 72 + col] = __float2bfloat16(eluf(acc[rg]));
    }
    __syncthreads();
    {   // g2
        const int col = 16 * w + ml;
        f32x4 p = (f32x4){0.f, 0.f, 0.f, 0.f};
        const bf16* wp = a.Wt_g1 + (size_t)col * 32 + quad * 8;
        #pragma unroll
        for (int ks = 0; ks < 2; ++ks) {
            const bf16x8 b  = *(const bf16x8*)(wp + (size_t)ks * 64 * 32);
            const bf16x8 av = *(const bf16x8*)(sG1 + ml * 72 + ks * 32 + quad * 8);
            p = __builtin_amdgcn_mfma_f32_16x16x32_bf16(av, b, p, 0, 0, 0);
        }
        const float bv = a.g_b1[col];
        #pragma unroll
        for (int rg = 0; rg < 4; ++rg)
            sG2[(quad * 4 + rg) * 72 + col] = __float2bfloat16(eluf(p[rg] + bv));
    }
    __syncthreads();
    if (w == 0) {   // logits
        f32x4 p = (f32x4){0.f, 0.f, 0.f, 0.f};
        const bf16* wp = a.Wt_g2 + (size_t)ml * 32 + quad * 8;
        #pragma unroll
        for (int ks = 0; ks < 2; ++ks) {
            const bf16x8 b  = *(const bf16x8*)(wp + (size_t)ks * 32 * 32);
            const bf16x8 av = *(const bf16x8*)(sG2 + ml * 72 + ks * 32 + quad * 8);
            p = __builtin_amdgcn_mfma_f32_16x16x32_bf16(av, b, p, 0, 0, 0);
        }
        const float bv = (ml < EXPERTS) ? a.g_b2[ml] : 0.f;
        #pragma unroll
        for (int rg = 0; rg < 4; ++rg)
            sLg[(quad * 4 + rg) * 16 + ml] = p[rg] + bv;
    }
    __syncthreads();
    if (tid < 16) {   // softmax
        float v[EXPERTS];
        float m = -1e30f;
        #pragma unroll
        for (int i = 0; i < EXPERTS; ++i) { v[i] = sLg[tid * 16 + i]; m = fmaxf(m, v[i]); }
        float s = 0.f;
        #pragma unroll
        for (int i = 0; i < EXPERTS; ++i) { v[i] = expf(v[i] - m); s += v[i]; }
        const float inv = 1.f / s;
        #pragma unroll
        for (int i = 0; i < EXPERTS; ++i) {
            sCo[i * 16 + tid] = v[i] * inv;
            if (g == 0) a.cobuf[(size_t)(row0 + tid) * EXPERTS + i] = v[i] * inv;
        }
    }
    __syncthreads();
    {   // d1
        f32x4 acc = wave_gemm<10, EXPERTS>(a.Wt_w0, 256, colg, sA, a.b0, 256, sCo, ml, quad);
        #pragma unroll
        for (int rg = 0; rg < 4; ++rg)
            a.d1buf[(size_t)(row0 + quad * 4 + rg) * 256 + colg] = __float2bfloat16(eluf(acc[rg]));
    }
}

// ---------------------------------------------------------------------------
// Decoder layer: dst = act(moe([z | src], W, b)).  WRF32: f32 out (M=267,
// Mtot=320, +tail tile for g==0,w==0) else bf16 [4096][256].
// ---------------------------------------------------------------------------
template<bool WRF32>
__global__ __launch_bounds__(256, 4) void dec_kernel(
    const bf16* __restrict__ zbuf, const bf16* __restrict__ src,
    const float* __restrict__ cobuf, const bf16* __restrict__ Wt,
    const float* __restrict__ bias, bf16* __restrict__ dstb,
    float* __restrict__ dstf)
{
    __shared__ bf16  sA[16 * STRA];
    __shared__ float sCo[16 * EXPERTS];
    const int tid = threadIdx.x;
    const int g = blockIdx.x, row0 = blockIdx.y * 16;
    const int w = tid >> 6, lane = tid & 63, ml = lane & 15, quad = lane >> 4;
    const int colg = g * 64 + 16 * w + ml;

    if (tid < 16 * EXPERTS) {
        const int e = tid >> 4, r = tid & 15;
        sCo[tid] = cobuf[(size_t)(row0 + r) * EXPERTS + e];
    }
    seg_bf16(sA, 0, zbuf, 32, 32, row0, tid);
    seg_bf16(sA, 32, src, 256, 256, row0, tid);
    __syncthreads();

    if constexpr (!WRF32) {
        f32x4 acc = wave_gemm<9, EXPERTS>(Wt, 256, colg, sA, bias, 256, sCo, ml, quad);
        #pragma unroll
        for (int rg = 0; rg < 4; ++rg)
            dstb[(size_t)(row0 + quad * 4 + rg) * 256 + colg] = __float2bfloat16(eluf(acc[rg]));
    } else {
        f32x4 acc = wave_gemm<9, EXPERTS>(Wt, 320, colg, sA, bias, FRAME, sCo, ml, quad);
        #pragma unroll
        for (int rg = 0; rg < 4; ++rg)
            if (colg < FRAME)
                dstf[(size_t)(row0 + quad * 4 + rg) * FRAME + colg] = acc[rg];
        if (g == 0 && w == 0) {   // tail cols 256..266
            const int col2 = 256 + ml;
            f32x4 a2 = wave_gemm<9, EXPERTS>(Wt, 320, col2, sA, bias, FRAME, sCo, ml, quad);
            #pragma unroll
            for (int rg = 0; rg < 4; ++rg)
                if (col2 < FRAME)
                    dstf[(size_t)(row0 + quad * 4 + rg) * FRAME + col2] = a2[rg];
        }
    }
}

// ---------------------------------------------------------------------------
extern "C" void kernel_launch(void* const* d_in, const int* in_sizes, int n_in,
                              void* d_out, int out_size, void* d_ws, size_t ws_size,
                              hipStream_t stream) {
    const float* x       = (const float*)d_in[0];
    const float* c       = (const float*)d_in[1];
    const float* eps     = (const float*)d_in[2];
    const float* enc_w1  = (const float*)d_in[3];
    const float* enc_b1  = (const float*)d_in[4];
    const float* enc_w2  = (const float*)d_in[5];
    const float* enc_b2  = (const float*)d_in[6];
    const float* enc_wmu = (const float*)d_in[7];
    const float* enc_bmu = (const float*)d_in[8];
    const float* enc_wlv = (const float*)d_in[9];
    const float* enc_blv = (const float*)d_in[10];
    const float* g_w0    = (const float*)d_in[11];
    const float* g_b0    = (const float*)d_in[12];
    const float* g_w1    = (const float*)d_in[13];
    const float* g_b1    = (const float*)d_in[14];
    const float* g_w2    = (const float*)d_in[15];
    const float* g_b2    = (const float*)d_in[16];
    const float* w0      = (const float*)d_in[17];
    const float* b0      = (const float*)d_in[18];
    const float* w1      = (const float*)d_in[19];
    const float* b1      = (const float*)d_in[20];
    const float* w2      = (const float*)d_in[21];
    const float* b2      = (const float*)d_in[22];

    // output (f32): [layer | mu | logvar]
    float* out_layer = (float*)d_out;
    float* out_mu    = out_layer + (size_t)N_BATCH * FRAME;
    float* out_lv    = out_mu    + (size_t)N_BATCH * LATENT;

    // ---- workspace ----
    char* p = (char*)d_ws;
    bf16* h1buf = (bf16*)p;  p += (size_t)N_BATCH * 256 * 2;
    bf16* h2buf = (bf16*)p;  p += (size_t)N_BATCH * 256 * 2;
    bf16* d1buf = (bf16*)p;  p += (size_t)N_BATCH * 256 * 2;
    bf16* d2buf = (bf16*)p;  p += (size_t)N_BATCH * 256 * 2;
    bf16* zbuf  = (bf16*)p;  p += (size_t)N_BATCH * 32 * 2;
    float* cobuf = (float*)p; p += (size_t)N_BATCH * EXPERTS * 4;
    bf16* Wt_e1 = (bf16*)p;  p += (size_t)18 * 256 * 32 * 2;
    bf16* Wt_e2 = (bf16*)p;  p += (size_t)17 * 256 * 32 * 2;
    bf16* Wt_ml = (bf16*)p;  p += (size_t)17 * 64 * 32 * 2;
    bf16* Wt_g0 = (bf16*)p;  p += (size_t)10 * 64 * 32 * 2;
    bf16* Wt_g1 = (bf16*)p;  p += (size_t)2 * 64 * 32 * 2;
    bf16* Wt_g2 = (bf16*)p;  p += (size_t)2 * 32 * 32 * 2;
    bf16* Wt_w0 = (bf16*)p;  p += (size_t)EXPERTS * 10 * 256 * 32 * 2;
    bf16* Wt_w1 = (bf16*)p;  p += (size_t)EXPERTS * 9 * 256 * 32 * 2;
    bf16* Wt_w2 = (bf16*)p;  p += (size_t)EXPERTS * 9 * 320 * 32 * 2;

    WTab tab;
    int cum = 0, n = 0;
    auto add = [&](const float* src, bf16* dst, int Ksrc, int Klen, int srcRow0,
                   int kBase, int kt0, int nKt, int Kst, int M, int Mtot, int mOff, int E) {
        const int Mtiles = (M + 31) / 32;
        tab.e[n] = {src, dst, Ksrc, Klen, srcRow0, kBase, kt0, nKt, Kst, M, Mtiles, Mtot, mOff, E, cum};
        cum += E * nKt * Mtiles;
        ++n;
    };
    //   src      dst     Ksrc Klen row0 kBase kt0 nKt Kst  M   Mtot mOff E
    add(enc_w1,  Wt_e1,  534, 267, 0,   0,    0,  9,  18, 256, 256, 0,  1);
    add(enc_w1,  Wt_e1,  534, 267, 267, 288,  9,  9,  18, 256, 256, 0,  1);
    add(enc_w2,  Wt_e2,  523, 267, 0,   0,    0,  9,  17, 256, 256, 0,  1);
    add(enc_w2,  Wt_e2,  523, 256, 267, 288,  9,  8,  17, 256, 256, 0,  1);
    add(enc_wmu, Wt_ml,  523, 267, 0,   0,    0,  9,  17, 32,  64,  0,  1);
    add(enc_wmu, Wt_ml,  523, 256, 267, 288,  9,  8,  17, 32,  64,  0,  1);
    add(enc_wlv, Wt_ml,  523, 267, 0,   0,    0,  9,  17, 32,  64,  32, 1);
    add(enc_wlv, Wt_ml,  523, 256, 267, 288,  9,  8,  17, 32,  64,  32, 1);
    add(g_w0,    Wt_g0,  299, 299, 0,   0,    0,  10, 10, 64,  64,  0,  1);
    add(g_w1,    Wt_g1,  64,  64,  0,   0,    0,  2,  2,  64,  64,  0,  1);
    add(g_w2,    Wt_g2,  64,  64,  0,   0,    0,  2,  2,  6,   32,  0,  1);
    add(w0,      Wt_w0,  299, 299, 0,   0,    0,  10, 10, 256, 256, 0,  EXPERTS);
    add(w1,      Wt_w1,  288, 288, 0,   0,    0,  9,  9,  256, 256, 0,  EXPERTS);
    add(w2,      Wt_w2,  288, 288, 0,   0,    0,  9,  9,  267, 320, 0,  EXPERTS);
    tab.total = cum;

    const dim3 blk(256);
    const dim3 grid(4, N_BATCH / 16);   // (4, 256) = 1024 blocks = 4/CU

    // 1) weight repack
    wtr_kernel<<<dim3(cum), blk, 0, stream>>>(tab);
    // 2) h1 = elu([x|0|c] @ W1 + b1)
    enc_kernel<18, true><<<grid, blk, 0, stream>>>(x, c, nullptr, Wt_e1, enc_b1, h1buf);
    // 3) h2 = elu([x|0|h1] @ W2 + b2)
    enc_kernel<17, false><<<grid, blk, 0, stream>>>(x, nullptr, h1buf, Wt_e2, enc_b2, h2buf);
    // 4) mid (mu|lv + z + gate + softmax) + d1
    MArgs m;
    m.x = x; m.c = c; m.eps = eps;
    m.enc_bmu = enc_bmu; m.enc_blv = enc_blv;
    m.g_b0 = g_b0; m.g_b1 = g_b1; m.g_b2 = g_b2; m.b0 = b0;
    m.h2buf = h2buf; m.Wt_ml = Wt_ml; m.Wt_g0 = Wt_g0; m.Wt_g1 = Wt_g1;
    m.Wt_g2 = Wt_g2; m.Wt_w0 = Wt_w0;
    m.out_mu = out_mu; m.out_lv = out_lv; m.cobuf = cobuf;
    m.zbuf = zbuf; m.d1buf = d1buf;
    mid_d1_kernel<<<grid, blk, 0, stream>>>(m);
    // 5) d2 = elu(moe([z|d1], w1, b1))
    dec_kernel<false><<<grid, blk, 0, stream>>>(zbuf, d1buf, cobuf, Wt_w1, b1, d2buf, nullptr);
    // 6) out = moe([z|d2], w2, b2) -> d_out (f32)
    dec_kernel<true><<<grid, blk, 0, stream>>>(zbuf, d2buf, cobuf, Wt_w2, b2, nullptr, out_layer);
}